// Round 11
// baseline (110.765 us; speedup 1.0000x reference)
//
#include <hip/hip_runtime.h>

#define NH 64

typedef _Float16 half8 __attribute__((ext_vector_type(8)));
typedef __fp16 fp16x2 __attribute__((ext_vector_type(2)));
typedef float float4v __attribute__((ext_vector_type(4)));

// tanh = 1 - 2/(e^{2x}+1): 5 ops (mul, exp, add, rcp, fma), no fabs/copysign.
// Handles both tails: e->0 => -1, e->inf => rcp=0 => +1. Abs err ~1e-7.
__device__ __forceinline__ float fast_tanh(float x) {
  float e = __expf(2.0f * x);
  float r = __builtin_amdgcn_rcpf(e + 1.0f);
  return fmaf(-2.0f, r, 1.0f);
}

// B = W2 packed in MFMA B-fragment lane order, split hi/lo f16:
// slot 0 = (f16)W2, slot 1 = (f16)(W2 - hi).  16 KB total -> L1-resident,
// so per-tile B loads are L1 hits (round-4 win). KEEP B IN GLOBAL: the
// LDS-fused variant (r6) regressed 41->45us (262k scattered ds_write_b16
// at 6 conflict-cycles each in the build phase + lgkm waits on reads).
// frag(s,nt,ks) at (s*8 + nt*2 + ks)*512 + lane*8 + jj, lane = quad*16+col,
// element (k_in = quad*8+jj + 32*ks, n = nt*16+col).
__global__ void prep_B(const float* __restrict__ W2, _Float16* __restrict__ ws) {
  int i = blockIdx.x * 256 + threadIdx.x;
  if (i >= 2 * 4096) return;
  int s = i >> 12;                 // 0 = hi, 1 = lo
  int off = i & 4095;
  int nt = off >> 10;
  int ks = (off >> 9) & 1;
  int ln = (off >> 3) & 63;
  int jj = off & 7;
  int h = ks * 32 + (ln >> 4) * 8 + jj;
  int j = nt * 16 + (ln & 15);
  float w2 = W2[h * NH + j];
  _Float16 hi = (_Float16)w2;
  ws[(s * 8 + nt * 2 + ks) * 512 + ln * 8 + jj] =
      (s == 0) ? hi : (_Float16)(w2 - (float)hi);
}

__device__ __forceinline__ half8 ldB(const _Float16* ws, int s, int nt, int ks, int lane) {
  return *(const half8*)(ws + (s * 8 + nt * 2 + ks) * 512 + lane * 8);
}

// ---- pipelined nt-loop machinery (all indices compile-time constants) ----
#define ZERO10(ACC) do { \
  ACC[0]=(float4v){0.f,0.f,0.f,0.f}; ACC[1]=(float4v){0.f,0.f,0.f,0.f}; \
  ACC[2]=(float4v){0.f,0.f,0.f,0.f}; ACC[3]=(float4v){0.f,0.f,0.f,0.f}; \
  ACC[4]=(float4v){0.f,0.f,0.f,0.f}; ACC[5]=(float4v){0.f,0.f,0.f,0.f}; \
  ACC[6]=(float4v){0.f,0.f,0.f,0.f}; ACC[7]=(float4v){0.f,0.f,0.f,0.f}; \
  ACC[8]=(float4v){0.f,0.f,0.f,0.f}; ACC[9]=(float4v){0.f,0.f,0.f,0.f}; \
} while(0)

#define MFMA_KS(NT, KS, ACC) do { \
  half8 bh = ldB(Bws, 0, NT, KS, lane); \
  half8 bl = ldB(Bws, 1, NT, KS, lane); \
  ACC[0] = __builtin_amdgcn_mfma_f32_16x16x32_f16(A0h[KS], bh, ACC[0], 0, 0, 0); \
  ACC[0] = __builtin_amdgcn_mfma_f32_16x16x32_f16(A0l[KS], bh, ACC[0], 0, 0, 0); \
  ACC[0] = __builtin_amdgcn_mfma_f32_16x16x32_f16(A0h[KS], bl, ACC[0], 0, 0, 0); \
  ACC[1] = __builtin_amdgcn_mfma_f32_16x16x32_f16(A1h[KS], bh, ACC[1], 0, 0, 0); \
  ACC[1] = __builtin_amdgcn_mfma_f32_16x16x32_f16(A1l[KS], bh, ACC[1], 0, 0, 0); \
  ACC[1] = __builtin_amdgcn_mfma_f32_16x16x32_f16(A1h[KS], bl, ACC[1], 0, 0, 0); \
  ACC[2] = __builtin_amdgcn_mfma_f32_16x16x32_f16(A2h[KS], bh, ACC[2], 0, 0, 0); \
  ACC[2] = __builtin_amdgcn_mfma_f32_16x16x32_f16(A2l[KS], bh, ACC[2], 0, 0, 0); \
  ACC[2] = __builtin_amdgcn_mfma_f32_16x16x32_f16(A2h[KS], bl, ACC[2], 0, 0, 0); \
  ACC[3] = __builtin_amdgcn_mfma_f32_16x16x32_f16(A3[KS], bh, ACC[3], 0, 0, 0); \
  ACC[4] = __builtin_amdgcn_mfma_f32_16x16x32_f16(A4[KS], bh, ACC[4], 0, 0, 0); \
  ACC[5] = __builtin_amdgcn_mfma_f32_16x16x32_f16(A5[KS], bh, ACC[5], 0, 0, 0); \
  ACC[6] = __builtin_amdgcn_mfma_f32_16x16x32_f16(A6[KS], bh, ACC[6], 0, 0, 0); \
  ACC[7] = __builtin_amdgcn_mfma_f32_16x16x32_f16(A7[KS], bh, ACC[7], 0, 0, 0); \
  ACC[8] = __builtin_amdgcn_mfma_f32_16x16x32_f16(A8[KS], bh, ACC[8], 0, 0, 0); \
  ACC[9] = __builtin_amdgcn_mfma_f32_16x16x32_f16(A9[KS], bh, ACC[9], 0, 0, 0); \
} while(0)

#define MFMA_BLOCK(NT, ACC) do { \
  ZERO10(ACC); MFMA_KS(NT, 0, ACC); MFMA_KS(NT, 1, ACC); \
} while(0)

// Faa di Bruno + W3, w3-prefolded: h1=w3*g1, h2n=-2*y2*h1, h3=h1*(4-6g1).
#define FDB_R(R, ACC, B2V, W3V) do { \
  float z0 = ACC[0][R] + B2V; \
  float y2 = fast_tanh(z0); \
  float g1 = fmaf(-y2, y2, 1.0f); \
  float h1 = W3V * g1; \
  float h2n = -2.0f * (y2 * h1); \
  float h3 = h1 * fmaf(-6.0f, g1, 4.0f); \
  float gp = ACC[1][R], gt = ACC[2][R]; \
  float gpp = ACC[3][R], gpt = ACC[4][R], gtt = ACC[5][R]; \
  float zppp = ACC[6][R], zppt = ACC[7][R], zptt = ACC[8][R], zttt = ACC[9][R]; \
  float c2p = h2n * gp, c2t = h2n * gt; \
  float c2p2 = c2p + c2p, c2t2 = c2t + c2t; \
  float gp2 = gp * gp, gt2 = gt * gt; \
  float h3p2 = h3 * gp2, h3t2 = h3 * gt2; \
  Tacc[0][R] = fmaf(h1, gp, Tacc[0][R]); \
  Tacc[1][R] = fmaf(h1, gt, Tacc[1][R]); \
  Tacc[2][R] = fmaf(c2p, gp, fmaf(h1, gpp, Tacc[2][R])); \
  Tacc[3][R] = fmaf(c2p, gt, fmaf(h1, gpt, Tacc[3][R])); \
  Tacc[4][R] = fmaf(c2t, gt, fmaf(h1, gtt, Tacc[4][R])); \
  Tacc[5][R] = fmaf(h3p2, gp, fmaf(c2p2 + c2p, gpp, fmaf(h1, zppp, Tacc[5][R]))); \
  Tacc[6][R] = fmaf(h3p2, gt, fmaf(c2p2, gpt, fmaf(c2t, gpp, fmaf(h1, zppt, Tacc[6][R])))); \
  Tacc[7][R] = fmaf(h3t2, gp, fmaf(c2t2, gpt, fmaf(c2p, gtt, fmaf(h1, zptt, Tacc[7][R])))); \
  Tacc[8][R] = fmaf(h3t2, gt, fmaf(c2t2 + c2t, gtt, fmaf(h1, zttt, Tacc[8][R]))); \
} while(0)

#define FDB(NT, ACC) do { \
  float b2v = b2a[NT], w3v = w3a[NT]; \
  FDB_R(0, ACC, b2v, w3v); FDB_R(1, ACC, b2v, w3v); \
  FDB_R(2, ACC, b2v, w3v); FDB_R(3, ACC, b2v, w3v); \
} while(0)

// 256 threads = 4 waves; wave w handles point-tile blockIdx*4+w (16 points).
// MFMA 16x16x32 f16: M=16 points, N=64 j (4 ntiles), K=64 h (2 ksteps).
// A-side kinds (mono_k(h) folded into A since it only depends on the K-dim):
//  0: y (hi/lo)   1: f1*a (hi/lo)   2: f1*b (hi/lo)
//  3..5: yf1*{-2a^2,-2ab,-2b^2}   6..9: f3*{a^3,a^2b,ab^2,b^3}
// hi/lo product split (3 MFMAs) on kinds 0..2; hi-only on kinds 3..9.
//
// waves_per_eu(2,2): live state now ~240 unified regs (arch + accA/accB);
// 2 waves/SIMD is the hard ceiling. (4)/(4,4)/512-thr variants all spilled
// ~0.5 GB/dispatch (68us -> 150-270us). DO NOT raise occupancy.
//
// Bench-number note: ~67us of dur_us is harness-fixed (256MB workspace
// re-poison fill at 82% HBM + graph overhead, present even when d_ws unused).
// Only pinn_mfma (+2us prep_B) is controllable.
//
// This round: SOFTWARE PIPELINE the nt loop. Old order [MFMA(nt); FdB(nt)]
// stalls the wave on its own MFMA results every iteration (VALU 59 / MFMA 16
// = ~25% idle issue slots at 2 waves/SIMD). Double-buffer acc (accA/accB)
// and issue MFMA(nt+1) BEFORE FdB(nt): MFMA pipe crunches nt+1 while VALU
// runs FdB on nt. FdB order over nt unchanged -> bit-identical output.
// Spill canary: FETCH>10MB means the +40 regs overflowed the 256 budget.
__global__ __launch_bounds__(256) __attribute__((amdgpu_waves_per_eu(2, 2)))
void pinn_mfma(
    const float* __restrict__ phi, const float* __restrict__ theta,
    const float* __restrict__ radius, const float* __restrict__ hth,
    const float* __restrict__ hph, const float* __restrict__ br,
    const float* __restrict__ W1, const float* __restrict__ b1,
    const float* __restrict__ b2, const float* __restrict__ W3,
    const _Float16* __restrict__ Bws, float* __restrict__ out, int n) {
  const int lane = threadIdx.x & 63;
  const int wave = threadIdx.x >> 6;
  const int tile = blockIdx.x * 4 + wave;
  const int quad = lane >> 4, col = lane & 15;
  const int pbase = tile * 16;
  if (pbase >= n) return;

  // ---- issue ALL global loads up-front (phi/theta, W1/b1 vectorized,
  //      epilogue scalars, b2/W3 rows) so latency overlaps A-gen compute ----
  float p = phi[pbase + col], t = theta[pbase + col];

  const float4v* W1v = (const float4v*)W1;   // W1[0][h]=a(h); W1[1][h]=W1[64+h]=b(h)
  const float4v* b1v = (const float4v*)b1;
  float4v aV[2][2], bV[2][2], cV[2][2];      // [ks][half-of-8], lane's h-run = quad*8..+7
  aV[0][0] = W1v[quad * 2];      aV[0][1] = W1v[quad * 2 + 1];
  aV[1][0] = W1v[8 + quad * 2];  aV[1][1] = W1v[8 + quad * 2 + 1];
  bV[0][0] = W1v[16 + quad * 2]; bV[0][1] = W1v[16 + quad * 2 + 1];
  bV[1][0] = W1v[24 + quad * 2]; bV[1][1] = W1v[24 + quad * 2 + 1];
  cV[0][0] = b1v[quad * 2];      cV[0][1] = b1v[quad * 2 + 1];
  cV[1][0] = b1v[8 + quad * 2];  cV[1][1] = b1v[8 + quad * 2 + 1];

  const int rsel = col >> 2;
  const int pi = pbase + quad * 4 + rsel;
  float t2 = theta[pi];
  float rv = radius[pi];
  float hthv = hth[pi], hphv = hph[pi], brv = br[pi];
  float b2a[4], w3a[4];
#pragma unroll
  for (int nt = 0; nt < 4; ++nt) {
    b2a[nt] = b2[nt * 16 + col];
    w3a[nt] = W3[nt * 16 + col];
  }

  // ---- A-fragments: lane's point m=col, h = 32*ks + quad*8 + jj ----
  half8 A0h[2], A0l[2], A1h[2], A1l[2], A2h[2], A2l[2];
  half8 A3[2], A4[2], A5[2], A6[2], A7[2], A8[2], A9[2];
#pragma unroll
  for (int ks = 0; ks < 2; ++ks) {
#pragma unroll
    for (int pp = 0; pp < 4; ++pp) {
      const int j0 = pp * 2, j1 = j0 + 1;
      float a0 = aV[ks][pp >> 1][j0 & 3], a1 = aV[ks][pp >> 1][j1 & 3];
      float b0 = bV[ks][pp >> 1][j0 & 3], b1_ = bV[ks][pp >> 1][j1 & 3];
      float c0 = cV[ks][pp >> 1][j0 & 3], c1 = cV[ks][pp >> 1][j1 & 3];
      float z_0 = fmaf(p, a0, fmaf(t, b0, c0));
      float z_1 = fmaf(p, a1, fmaf(t, b1_, c1));
      float y_0 = fast_tanh(z_0), y_1 = fast_tanh(z_1);
      float f1_0 = fmaf(-y_0, y_0, 1.0f), f1_1 = fmaf(-y_1, y_1, 1.0f);
      float f3_0 = f1_0 * fmaf(-6.0f, f1_0, 4.0f);
      float f3_1 = f1_1 * fmaf(-6.0f, f1_1, 4.0f);
      float na_0 = -2.0f * (y_0 * f1_0), na_1 = -2.0f * (y_1 * f1_1);
      float a2_0 = a0 * a0, a2_1 = a1 * a1;
      float ab_0 = a0 * b0, ab_1 = a1 * b1_;
      float bb_0 = b0 * b0, bb_1 = b1_ * b1_;
      float f3a2_0 = f3_0 * a2_0, f3a2_1 = f3_1 * a2_1;
      float f3bb_0 = f3_0 * bb_0, f3bb_1 = f3_1 * bb_1;
      float v1_0 = f1_0 * a0, v1_1 = f1_1 * a1;
      float v2_0 = f1_0 * b0, v2_1 = f1_1 * b1_;
      fp16x2 ph, plv;
      ph = __builtin_amdgcn_cvt_pkrtz(y_0, y_1);
      A0h[ks][j0] = (_Float16)ph[0]; A0h[ks][j1] = (_Float16)ph[1];
      plv = __builtin_amdgcn_cvt_pkrtz(y_0 - (float)ph[0], y_1 - (float)ph[1]);
      A0l[ks][j0] = (_Float16)plv[0]; A0l[ks][j1] = (_Float16)plv[1];
      ph = __builtin_amdgcn_cvt_pkrtz(v1_0, v1_1);
      A1h[ks][j0] = (_Float16)ph[0]; A1h[ks][j1] = (_Float16)ph[1];
      plv = __builtin_amdgcn_cvt_pkrtz(v1_0 - (float)ph[0], v1_1 - (float)ph[1]);
      A1l[ks][j0] = (_Float16)plv[0]; A1l[ks][j1] = (_Float16)plv[1];
      ph = __builtin_amdgcn_cvt_pkrtz(v2_0, v2_1);
      A2h[ks][j0] = (_Float16)ph[0]; A2h[ks][j1] = (_Float16)ph[1];
      plv = __builtin_amdgcn_cvt_pkrtz(v2_0 - (float)ph[0], v2_1 - (float)ph[1]);
      A2l[ks][j0] = (_Float16)plv[0]; A2l[ks][j1] = (_Float16)plv[1];
      A3[ks][j0] = (_Float16)(na_0 * a2_0);  A3[ks][j1] = (_Float16)(na_1 * a2_1);
      A4[ks][j0] = (_Float16)(na_0 * ab_0);  A4[ks][j1] = (_Float16)(na_1 * ab_1);
      A5[ks][j0] = (_Float16)(na_0 * bb_0);  A5[ks][j1] = (_Float16)(na_1 * bb_1);
      A6[ks][j0] = (_Float16)(f3a2_0 * a0);  A6[ks][j1] = (_Float16)(f3a2_1 * a1);
      A7[ks][j0] = (_Float16)(f3a2_0 * b0);  A7[ks][j1] = (_Float16)(f3a2_1 * b1_);
      A8[ks][j0] = (_Float16)(f3bb_0 * a0);  A8[ks][j1] = (_Float16)(f3bb_1 * a1);
      A9[ks][j0] = (_Float16)(f3bb_0 * b0);  A9[ks][j1] = (_Float16)(f3bb_1 * b1_);
    }
  }

  float4v Tacc[9];
#pragma unroll
  for (int x = 0; x < 9; ++x) Tacc[x] = (float4v){0.f, 0.f, 0.f, 0.f};

  // ---- pipelined nt loop: MFMA(nt+1) issued before FdB(nt) ----
  float4v accA[10], accB[10];
  MFMA_BLOCK(0, accA);
  MFMA_BLOCK(1, accB);
  FDB(0, accA);
  MFMA_BLOCK(2, accA);
  FDB(1, accB);
  MFMA_BLOCK(3, accB);
  FDB(2, accA);
  FDB(3, accB);

  // ---- fold-butterfly reduce over the 16 cols ----
  // Step 1 (xor 8) folds the r0/r1-vs-r2/r3 selection into the exchange;
  // step 2 (xor 4) folds r-within-pair; steps 3-4 finish the sum.
  // Result: lane col holds T_x for r = col>>2; (col&3)==0 lanes store.
  float T[9];
#pragma unroll
  for (int x = 0; x < 9; ++x) {
    float4v v = Tacc[x];
    bool hi8 = (col & 8) != 0;
    float k0 = hi8 ? v[2] : v[0];
    float k1 = hi8 ? v[3] : v[1];
    float s0 = hi8 ? v[0] : v[2];
    float s1 = hi8 ? v[1] : v[3];
    float p0 = k0 + __shfl_xor(s0, 8, 16);
    float p1 = k1 + __shfl_xor(s1, 8, 16);
    bool hi4 = (col & 4) != 0;
    float kk = hi4 ? p1 : p0;
    float ss = hi4 ? p0 : p1;
    float q = kk + __shfl_xor(ss, 4, 16);
    q += __shfl_xor(q, 2, 16);
    q += __shfl_xor(q, 1, 16);
    T[x] = q;
  }
  float Tp = T[0], Tt = T[1], Tpp = T[2], Tpt = T[3], Ttt = T[4];
  float Tppp = T[5], Tppt = T[6], Tptt = T[7], Tttt = T[8];

  // v_sin/v_cos take REVOLUTIONS; theta in (0.1, pi-0.1) needs no reduction.
  float rev = t2 * 0.15915494309189535f;
  float s = __builtin_amdgcn_sinf(rev);
  float c = __builtin_amdgcn_cosf(rev);
  float inv_s = __builtin_amdgcn_rcpf(s);
  float inv_s2 = inv_s * inv_s;

  float A = Tp * inv_s + Tt;          // u_theta
  float D = Tp * inv_s - Tt;          // u_phi
  float q1 = Tpt * inv_s - Tp * c * inv_s2;
  float A_t = q1 + Ttt;
  float D_t = q1 - Ttt;
  float q2 = Tptt * inv_s - 2.0f * Tpt * c * inv_s2
           + Tp * fmaf(c, c, 1.0f) * inv_s2 * inv_s;   // s^2+2c^2 = 1+c^2
  float A_tt = q2 + Tttt;
  float D_tt = q2 - Tttt;
  float A_pp = Tppp * inv_s + Tppt;
  float D_p  = Tpp * inv_s - Tpt;
  float D_pp = Tppp * inv_s - Tppt;

  float utt   = -(A_t * s + A * c);
  float uttt  = -(A_tt * s + 2.0f * A_t * c - A * s) * s + utt * c;
  float utpp  = -A_pp;
  float upht  = D_t * s + D * c;
  float uphtt = (D_tt * s + 2.0f * D_t * c - D * s) * s + upht * c;
  float upp   = D_p;
  float uppp  = D_pp;

  float inv_r = __builtin_amdgcn_rcpf(rv);
  float inv_r2 = inv_r * inv_r;
  float div_uh = (utt + upp) * inv_r * inv_s;
  float lap_t = s * inv_r2 * uttt + utpp * inv_s2 * inv_r2;
  float lap_p = s * inv_r2 * uphtt + uppp * inv_s2 * inv_r2;
  float comp = s * (lap_t * lap_t + lap_p * lap_p);
  float sv = -(A * hthv + D * hphv) - brv * div_uh;
  float tg = div_uh - A * s * __builtin_amdgcn_rcpf(c) * inv_r;

  if ((col & 3) == 0) {
    out[pi]         = A;
    out[n + pi]     = D;
    out[2 * n + pi] = div_uh;
    out[3 * n + pi] = sv;
    out[4 * n + pi] = tg;
    out[5 * n + pi] = comp;
  }
}

extern "C" void kernel_launch(void* const* d_in, const int* in_sizes, int n_in,
                              void* d_out, int out_size, void* d_ws, size_t ws_size,
                              hipStream_t stream) {
  const float* phi    = (const float*)d_in[0];
  const float* theta  = (const float*)d_in[1];
  const float* radius = (const float*)d_in[2];
  const float* hth    = (const float*)d_in[3];
  const float* hph    = (const float*)d_in[4];
  const float* br     = (const float*)d_in[5];
  const float* W1     = (const float*)d_in[6];
  const float* b1     = (const float*)d_in[7];
  const float* W2     = (const float*)d_in[8];
  const float* b2     = (const float*)d_in[9];
  const float* W3     = (const float*)d_in[10];
  (void)ws_size; (void)n_in; (void)out_size;

  _Float16* Bws = (_Float16*)d_ws;     // 2 slots * 4 nt * 2 ks * 512 halfs = 16 KB
  float* out = (float*)d_out;
  int n = in_sizes[0];

  prep_B<<<(2 * 4096 + 255) / 256, 256, 0, stream>>>(W2, Bws);
  int ntiles = (n + 15) / 16;
  int nblocks = (ntiles + 3) / 4;
  pinn_mfma<<<nblocks, 256, 0, stream>>>(
      phi, theta, radius, hth, hph, br, W1, b1, b2, W3, Bws, out, n);
}

// Round 12
// 106.320 us; speedup vs baseline: 1.0418x; 1.0418x over previous
//
#include <hip/hip_runtime.h>

#define NH 64

typedef _Float16 half8 __attribute__((ext_vector_type(8)));
typedef __fp16 fp16x2 __attribute__((ext_vector_type(2)));
typedef float float4v __attribute__((ext_vector_type(4)));

// tanh = 1 - 2/(e^{2x}+1): 5 ops (mul, exp, add, rcp, fma), no fabs/copysign.
// Handles both tails: e->0 => -1, e->inf => rcp=0 => +1. Abs err ~1e-7.
__device__ __forceinline__ float fast_tanh(float x) {
  float e = __expf(2.0f * x);
  float r = __builtin_amdgcn_rcpf(e + 1.0f);
  return fmaf(-2.0f, r, 1.0f);
}

// B = W2 packed in MFMA B-fragment lane order, split hi/lo f16:
// slot 0 = (f16)W2, slot 1 = (f16)(W2 - hi).  16 KB total -> L1-resident,
// so per-tile B loads are L1 hits (round-4 win). KEEP B IN GLOBAL: the
// LDS-fused variant (r6) regressed 41->45us (262k scattered ds_write_b16
// at 6 conflict-cycles each in the build phase + lgkm waits on reads).
// frag(s,nt,ks) at (s*8 + nt*2 + ks)*512 + lane*8 + jj, lane = quad*16+col,
// element (k_in = quad*8+jj + 32*ks, n = nt*16+col).
__global__ void prep_B(const float* __restrict__ W2, _Float16* __restrict__ ws) {
  int i = blockIdx.x * 256 + threadIdx.x;
  if (i >= 2 * 4096) return;
  int s = i >> 12;                 // 0 = hi, 1 = lo
  int off = i & 4095;
  int nt = off >> 10;
  int ks = (off >> 9) & 1;
  int ln = (off >> 3) & 63;
  int jj = off & 7;
  int h = ks * 32 + (ln >> 4) * 8 + jj;
  int j = nt * 16 + (ln & 15);
  float w2 = W2[h * NH + j];
  _Float16 hi = (_Float16)w2;
  ws[(s * 8 + nt * 2 + ks) * 512 + ln * 8 + jj] =
      (s == 0) ? hi : (_Float16)(w2 - (float)hi);
}

__device__ __forceinline__ half8 ldB(const _Float16* ws, int s, int nt, int ks, int lane) {
  return *(const half8*)(ws + (s * 8 + nt * 2 + ks) * 512 + lane * 8);
}

// 256 threads = 4 waves; wave w handles point-tile blockIdx*4+w (16 points).
// MFMA 16x16x32 f16: M=16 points, N=64 j (4 ntiles), K=64 h (2 ksteps).
// A-side kinds (mono_k(h) folded into A since it only depends on the K-dim):
//  0: y (hi/lo)   1: f1*a (hi/lo)   2: f1*b (hi/lo)
//  3..5: yf1*{-2a^2,-2ab,-2b^2}   6..9: f3*{a^3,a^2b,ab^2,b^3}
// hi/lo product split (3 MFMAs) on kinds 0..2; hi-only on kinds 3..9.
//
// waves_per_eu(2,2): live state ~200 unified regs (124 arch + ~76 accum);
// 512/200 = 2 waves/SIMD is the hard ceiling. (4)/(4,4)/512-thr variants all
// spilled ~0.5 GB/dispatch (68us -> 150-270us). DO NOT raise occupancy.
//
// STRUCTURAL LEDGER (what's been tried and measured):
//  - occupancy raise: spills (r1/r2/r3).  - LDS B-table: bank conflicts (r6).
//  - manual SW pipeline accA/accB: neutral-negative (r11, VALU 59->50,
//    compiler already interleaves the unrolled nt loop). KEEP compiler order.
// Kernel floor is latency-bound at the 2-wave/SIMD register wall; ~67us of
// the bench dur is harness-fixed (256MB re-poison fills at 83% HBM).
__global__ __launch_bounds__(256) __attribute__((amdgpu_waves_per_eu(2, 2)))
void pinn_mfma(
    const float* __restrict__ phi, const float* __restrict__ theta,
    const float* __restrict__ radius, const float* __restrict__ hth,
    const float* __restrict__ hph, const float* __restrict__ br,
    const float* __restrict__ W1, const float* __restrict__ b1,
    const float* __restrict__ b2, const float* __restrict__ W3,
    const _Float16* __restrict__ Bws, float* __restrict__ out, int n) {
  const int lane = threadIdx.x & 63;
  const int wave = threadIdx.x >> 6;
  const int tile = blockIdx.x * 4 + wave;
  const int quad = lane >> 4, col = lane & 15;
  const int pbase = tile * 16;
  if (pbase >= n) return;

  // ---- issue ALL global loads up-front (phi/theta, W1/b1 vectorized,
  //      epilogue scalars, b2/W3 rows) so latency overlaps A-gen compute ----
  float p = phi[pbase + col], t = theta[pbase + col];

  const float4v* W1v = (const float4v*)W1;   // W1[0][h]=a(h); W1[1][h]=W1[64+h]=b(h)
  const float4v* b1v = (const float4v*)b1;
  float4v aV[2][2], bV[2][2], cV[2][2];      // [ks][half-of-8], lane's h-run = quad*8..+7
  aV[0][0] = W1v[quad * 2];      aV[0][1] = W1v[quad * 2 + 1];
  aV[1][0] = W1v[8 + quad * 2];  aV[1][1] = W1v[8 + quad * 2 + 1];
  bV[0][0] = W1v[16 + quad * 2]; bV[0][1] = W1v[16 + quad * 2 + 1];
  bV[1][0] = W1v[24 + quad * 2]; bV[1][1] = W1v[24 + quad * 2 + 1];
  cV[0][0] = b1v[quad * 2];      cV[0][1] = b1v[quad * 2 + 1];
  cV[1][0] = b1v[8 + quad * 2];  cV[1][1] = b1v[8 + quad * 2 + 1];

  const int rsel = col >> 2;
  const int pi = pbase + quad * 4 + rsel;
  float t2 = theta[pi];
  float rv = radius[pi];
  float hthv = hth[pi], hphv = hph[pi], brv = br[pi];
  float b2a[4], w3a[4];
#pragma unroll
  for (int nt = 0; nt < 4; ++nt) {
    b2a[nt] = b2[nt * 16 + col];
    w3a[nt] = W3[nt * 16 + col];
  }

  // ---- A-fragments: lane's point m=col, h = 32*ks + quad*8 + jj ----
  half8 A0h[2], A0l[2], A1h[2], A1l[2], A2h[2], A2l[2];
  half8 A3[2], A4[2], A5[2], A6[2], A7[2], A8[2], A9[2];
#pragma unroll
  for (int ks = 0; ks < 2; ++ks) {
#pragma unroll
    for (int pp = 0; pp < 4; ++pp) {
      const int j0 = pp * 2, j1 = j0 + 1;
      float a0 = aV[ks][pp >> 1][j0 & 3], a1 = aV[ks][pp >> 1][j1 & 3];
      float b0 = bV[ks][pp >> 1][j0 & 3], b1_ = bV[ks][pp >> 1][j1 & 3];
      float c0 = cV[ks][pp >> 1][j0 & 3], c1 = cV[ks][pp >> 1][j1 & 3];
      float z_0 = fmaf(p, a0, fmaf(t, b0, c0));
      float z_1 = fmaf(p, a1, fmaf(t, b1_, c1));
      float y_0 = fast_tanh(z_0), y_1 = fast_tanh(z_1);
      float f1_0 = fmaf(-y_0, y_0, 1.0f), f1_1 = fmaf(-y_1, y_1, 1.0f);
      float f3_0 = f1_0 * fmaf(-6.0f, f1_0, 4.0f);
      float f3_1 = f1_1 * fmaf(-6.0f, f1_1, 4.0f);
      float na_0 = -2.0f * (y_0 * f1_0), na_1 = -2.0f * (y_1 * f1_1);
      float a2_0 = a0 * a0, a2_1 = a1 * a1;
      float ab_0 = a0 * b0, ab_1 = a1 * b1_;
      float bb_0 = b0 * b0, bb_1 = b1_ * b1_;
      float f3a2_0 = f3_0 * a2_0, f3a2_1 = f3_1 * a2_1;
      float f3bb_0 = f3_0 * bb_0, f3bb_1 = f3_1 * bb_1;
      float v1_0 = f1_0 * a0, v1_1 = f1_1 * a1;
      float v2_0 = f1_0 * b0, v2_1 = f1_1 * b1_;
      fp16x2 ph, plv;
      ph = __builtin_amdgcn_cvt_pkrtz(y_0, y_1);
      A0h[ks][j0] = (_Float16)ph[0]; A0h[ks][j1] = (_Float16)ph[1];
      plv = __builtin_amdgcn_cvt_pkrtz(y_0 - (float)ph[0], y_1 - (float)ph[1]);
      A0l[ks][j0] = (_Float16)plv[0]; A0l[ks][j1] = (_Float16)plv[1];
      ph = __builtin_amdgcn_cvt_pkrtz(v1_0, v1_1);
      A1h[ks][j0] = (_Float16)ph[0]; A1h[ks][j1] = (_Float16)ph[1];
      plv = __builtin_amdgcn_cvt_pkrtz(v1_0 - (float)ph[0], v1_1 - (float)ph[1]);
      A1l[ks][j0] = (_Float16)plv[0]; A1l[ks][j1] = (_Float16)plv[1];
      ph = __builtin_amdgcn_cvt_pkrtz(v2_0, v2_1);
      A2h[ks][j0] = (_Float16)ph[0]; A2h[ks][j1] = (_Float16)ph[1];
      plv = __builtin_amdgcn_cvt_pkrtz(v2_0 - (float)ph[0], v2_1 - (float)ph[1]);
      A2l[ks][j0] = (_Float16)plv[0]; A2l[ks][j1] = (_Float16)plv[1];
      A3[ks][j0] = (_Float16)(na_0 * a2_0);  A3[ks][j1] = (_Float16)(na_1 * a2_1);
      A4[ks][j0] = (_Float16)(na_0 * ab_0);  A4[ks][j1] = (_Float16)(na_1 * ab_1);
      A5[ks][j0] = (_Float16)(na_0 * bb_0);  A5[ks][j1] = (_Float16)(na_1 * bb_1);
      A6[ks][j0] = (_Float16)(f3a2_0 * a0);  A6[ks][j1] = (_Float16)(f3a2_1 * a1);
      A7[ks][j0] = (_Float16)(f3a2_0 * b0);  A7[ks][j1] = (_Float16)(f3a2_1 * b1_);
      A8[ks][j0] = (_Float16)(f3bb_0 * a0);  A8[ks][j1] = (_Float16)(f3bb_1 * a1);
      A9[ks][j0] = (_Float16)(f3bb_0 * b0);  A9[ks][j1] = (_Float16)(f3bb_1 * b1_);
    }
  }

  float4v Tacc[9];
#pragma unroll
  for (int x = 0; x < 9; ++x) Tacc[x] = (float4v){0.f, 0.f, 0.f, 0.f};

#pragma unroll
  for (int nt = 0; nt < 4; ++nt) {
    float4v acc[10];
#pragma unroll
    for (int k = 0; k < 10; ++k) acc[k] = (float4v){0.f, 0.f, 0.f, 0.f};
#pragma unroll
    for (int ks = 0; ks < 2; ++ks) {
      half8 bh = ldB(Bws, 0, nt, ks, lane);
      half8 bl = ldB(Bws, 1, nt, ks, lane);
      acc[0] = __builtin_amdgcn_mfma_f32_16x16x32_f16(A0h[ks], bh, acc[0], 0, 0, 0);
      acc[0] = __builtin_amdgcn_mfma_f32_16x16x32_f16(A0l[ks], bh, acc[0], 0, 0, 0);
      acc[0] = __builtin_amdgcn_mfma_f32_16x16x32_f16(A0h[ks], bl, acc[0], 0, 0, 0);
      acc[1] = __builtin_amdgcn_mfma_f32_16x16x32_f16(A1h[ks], bh, acc[1], 0, 0, 0);
      acc[1] = __builtin_amdgcn_mfma_f32_16x16x32_f16(A1l[ks], bh, acc[1], 0, 0, 0);
      acc[1] = __builtin_amdgcn_mfma_f32_16x16x32_f16(A1h[ks], bl, acc[1], 0, 0, 0);
      acc[2] = __builtin_amdgcn_mfma_f32_16x16x32_f16(A2h[ks], bh, acc[2], 0, 0, 0);
      acc[2] = __builtin_amdgcn_mfma_f32_16x16x32_f16(A2l[ks], bh, acc[2], 0, 0, 0);
      acc[2] = __builtin_amdgcn_mfma_f32_16x16x32_f16(A2h[ks], bl, acc[2], 0, 0, 0);
      acc[3] = __builtin_amdgcn_mfma_f32_16x16x32_f16(A3[ks], bh, acc[3], 0, 0, 0);
      acc[4] = __builtin_amdgcn_mfma_f32_16x16x32_f16(A4[ks], bh, acc[4], 0, 0, 0);
      acc[5] = __builtin_amdgcn_mfma_f32_16x16x32_f16(A5[ks], bh, acc[5], 0, 0, 0);
      acc[6] = __builtin_amdgcn_mfma_f32_16x16x32_f16(A6[ks], bh, acc[6], 0, 0, 0);
      acc[7] = __builtin_amdgcn_mfma_f32_16x16x32_f16(A7[ks], bh, acc[7], 0, 0, 0);
      acc[8] = __builtin_amdgcn_mfma_f32_16x16x32_f16(A8[ks], bh, acc[8], 0, 0, 0);
      acc[9] = __builtin_amdgcn_mfma_f32_16x16x32_f16(A9[ks], bh, acc[9], 0, 0, 0);
    }
    // ---- Faa di Bruno + W3, w3-prefolded: h1=w3*g1, h2n=-2*y2*h1, h3=h1*(4-6g1).
    // Every T-line is a pure fma chain into Tacc (no outer w3 multiply).
    float b2v = b2a[nt];
    float w3v = w3a[nt];
#pragma unroll
    for (int r = 0; r < 4; ++r) {
      float z0 = acc[0][r] + b2v;
      float y2 = fast_tanh(z0);
      float g1 = fmaf(-y2, y2, 1.0f);
      float h1 = w3v * g1;
      float h2n = -2.0f * (y2 * h1);
      float h3 = h1 * fmaf(-6.0f, g1, 4.0f);
      float gp = acc[1][r], gt = acc[2][r];
      float gpp = acc[3][r], gpt = acc[4][r], gtt = acc[5][r];
      float zppp = acc[6][r], zppt = acc[7][r], zptt = acc[8][r], zttt = acc[9][r];
      float c2p = h2n * gp, c2t = h2n * gt;
      float c2p2 = c2p + c2p, c2t2 = c2t + c2t;
      float gp2 = gp * gp, gt2 = gt * gt;
      float h3p2 = h3 * gp2, h3t2 = h3 * gt2;
      Tacc[0][r] = fmaf(h1, gp, Tacc[0][r]);
      Tacc[1][r] = fmaf(h1, gt, Tacc[1][r]);
      Tacc[2][r] = fmaf(c2p, gp, fmaf(h1, gpp, Tacc[2][r]));
      Tacc[3][r] = fmaf(c2p, gt, fmaf(h1, gpt, Tacc[3][r]));
      Tacc[4][r] = fmaf(c2t, gt, fmaf(h1, gtt, Tacc[4][r]));
      Tacc[5][r] = fmaf(h3p2, gp, fmaf(c2p2 + c2p, gpp, fmaf(h1, zppp, Tacc[5][r])));
      Tacc[6][r] = fmaf(h3p2, gt, fmaf(c2p2, gpt, fmaf(c2t, gpp, fmaf(h1, zppt, Tacc[6][r]))));
      Tacc[7][r] = fmaf(h3t2, gp, fmaf(c2t2, gpt, fmaf(c2p, gtt, fmaf(h1, zptt, Tacc[7][r]))));
      Tacc[8][r] = fmaf(h3t2, gt, fmaf(c2t2 + c2t, gtt, fmaf(h1, zttt, Tacc[8][r])));
    }
  }

  // ---- fold-butterfly reduce over the 16 cols ----
  // Step 1 (xor 8) folds the r0/r1-vs-r2/r3 selection into the exchange;
  // step 2 (xor 4) folds r-within-pair; steps 3-4 finish the sum.
  // Result: lane col holds T_x for r = col>>2; (col&3)==0 lanes store.
  float T[9];
#pragma unroll
  for (int x = 0; x < 9; ++x) {
    float4v v = Tacc[x];
    bool hi8 = (col & 8) != 0;
    float k0 = hi8 ? v[2] : v[0];
    float k1 = hi8 ? v[3] : v[1];
    float s0 = hi8 ? v[0] : v[2];
    float s1 = hi8 ? v[1] : v[3];
    float p0 = k0 + __shfl_xor(s0, 8, 16);
    float p1 = k1 + __shfl_xor(s1, 8, 16);
    bool hi4 = (col & 4) != 0;
    float kk = hi4 ? p1 : p0;
    float ss = hi4 ? p0 : p1;
    float q = kk + __shfl_xor(ss, 4, 16);
    q += __shfl_xor(q, 2, 16);
    q += __shfl_xor(q, 1, 16);
    T[x] = q;
  }
  float Tp = T[0], Tt = T[1], Tpp = T[2], Tpt = T[3], Ttt = T[4];
  float Tppp = T[5], Tppt = T[6], Tptt = T[7], Tttt = T[8];

  // v_sin/v_cos take REVOLUTIONS; theta in (0.1, pi-0.1) needs no reduction.
  float rev = t2 * 0.15915494309189535f;
  float s = __builtin_amdgcn_sinf(rev);
  float c = __builtin_amdgcn_cosf(rev);
  float inv_s = __builtin_amdgcn_rcpf(s);
  float inv_s2 = inv_s * inv_s;

  float A = Tp * inv_s + Tt;          // u_theta
  float D = Tp * inv_s - Tt;          // u_phi
  float q1 = Tpt * inv_s - Tp * c * inv_s2;
  float A_t = q1 + Ttt;
  float D_t = q1 - Ttt;
  float q2 = Tptt * inv_s - 2.0f * Tpt * c * inv_s2
           + Tp * fmaf(c, c, 1.0f) * inv_s2 * inv_s;   // s^2+2c^2 = 1+c^2
  float A_tt = q2 + Tttt;
  float D_tt = q2 - Tttt;
  float A_pp = Tppp * inv_s + Tppt;
  float D_p  = Tpp * inv_s - Tpt;
  float D_pp = Tppp * inv_s - Tppt;

  float utt   = -(A_t * s + A * c);
  float uttt  = -(A_tt * s + 2.0f * A_t * c - A * s) * s + utt * c;
  float utpp  = -A_pp;
  float upht  = D_t * s + D * c;
  float uphtt = (D_tt * s + 2.0f * D_t * c - D * s) * s + upht * c;
  float upp   = D_p;
  float uppp  = D_pp;

  float inv_r = __builtin_amdgcn_rcpf(rv);
  float inv_r2 = inv_r * inv_r;
  float div_uh = (utt + upp) * inv_r * inv_s;
  float lap_t = s * inv_r2 * uttt + utpp * inv_s2 * inv_r2;
  float lap_p = s * inv_r2 * uphtt + uppp * inv_s2 * inv_r2;
  float comp = s * (lap_t * lap_t + lap_p * lap_p);
  float sv = -(A * hthv + D * hphv) - brv * div_uh;
  float tg = div_uh - A * s * __builtin_amdgcn_rcpf(c) * inv_r;

  if ((col & 3) == 0) {
    out[pi]         = A;
    out[n + pi]     = D;
    out[2 * n + pi] = div_uh;
    out[3 * n + pi] = sv;
    out[4 * n + pi] = tg;
    out[5 * n + pi] = comp;
  }
}

extern "C" void kernel_launch(void* const* d_in, const int* in_sizes, int n_in,
                              void* d_out, int out_size, void* d_ws, size_t ws_size,
                              hipStream_t stream) {
  const float* phi    = (const float*)d_in[0];
  const float* theta  = (const float*)d_in[1];
  const float* radius = (const float*)d_in[2];
  const float* hth    = (const float*)d_in[3];
  const float* hph    = (const float*)d_in[4];
  const float* br     = (const float*)d_in[5];
  const float* W1     = (const float*)d_in[6];
  const float* b1     = (const float*)d_in[7];
  const float* W2     = (const float*)d_in[8];
  const float* b2     = (const float*)d_in[9];
  const float* W3     = (const float*)d_in[10];
  (void)ws_size; (void)n_in; (void)out_size;

  _Float16* Bws = (_Float16*)d_ws;     // 2 slots * 4 nt * 2 ks * 512 halfs = 16 KB
  float* out = (float*)d_out;
  int n = in_sizes[0];

  prep_B<<<(2 * 4096 + 255) / 256, 256, 0, stream>>>(W2, Bws);
  int ntiles = (n + 15) / 16;
  int nblocks = (ntiles + 3) / 4;
  pinn_mfma<<<nblocks, 256, 0, stream>>>(
      phi, theta, radius, hth, hph, br, W1, b1, b2, W3, Bws, out, n);
}